// Round 4
// baseline (254.247 us; speedup 1.0000x reference)
//
#include <hip/hip_runtime.h>

// LSSM: x_t = x_{t-1} A^T + u_t B^T ; y_t = x_t C^T + u_t D^T ; x_0 = 0
// B=16, SEQ=8192, all dims 128.
//
// R4: swapped-state per-wave scan. State X^T [128 x 16(batch)]; each chunk is
// owned by ONE wave (w0) with A,B as in-register MFMA A-operand fragments;
// state crosses steps via a packed hi/lo bf16 LDS round-trip (b64 writes /
// b128 reads, same wave). A partner wave (w1) holds C,D, stages u coalesced,
// and emits y one step behind (one 2-wave barrier per step). 2-pass structure
// with a 3-stage combine tree (P = A^CL, hi/lo 3-product for accuracy).

#define SEQ 8192
#define DD  128
#define CL  16
#define NC  512
#define GRP 16
#define NG  32

typedef __bf16 bf16t;
typedef __bf16 bf16x8 __attribute__((ext_vector_type(8)));
typedef float  f32x4  __attribute__((ext_vector_type(4)));
typedef unsigned int u32;
typedef u32 u32x2 __attribute__((ext_vector_type(2)));
typedef u32 u32x4 __attribute__((ext_vector_type(4)));

#define MFMA(a,b,c) __builtin_amdgcn_mfma_f32_16x16x32_bf16(a,b,c,0,0,0)

__device__ __forceinline__ u32 pkbf(float a, float b) {
    u32 ha = (u32)__builtin_bit_cast(unsigned short, (bf16t)a);
    u32 hb = (u32)__builtin_bit_cast(unsigned short, (bf16t)b);
    return ha | (hb << 16);
}
__device__ __forceinline__ float lo_f(u32 p) { return __uint_as_float(p << 16); }
__device__ __forceinline__ float hi_f(u32 p) { return __uint_as_float(p & 0xffff0000u); }

__device__ __forceinline__ bf16x8 ld8(const float* __restrict__ p) {
    float4 a = *(const float4*)p;
    float4 b = *(const float4*)(p + 4);
    bf16x8 r;
    r[0]=(bf16t)a.x; r[1]=(bf16t)a.y; r[2]=(bf16t)a.z; r[3]=(bf16t)a.w;
    r[4]=(bf16t)b.x; r[5]=(bf16t)b.y; r[6]=(bf16t)b.z; r[7]=(bf16t)b.w;
    return r;
}
__device__ __forceinline__ void ld8hl(const float* __restrict__ p, bf16x8& h, bf16x8& l) {
    float4 a = *(const float4*)p;
    float4 b = *(const float4*)(p + 4);
    float v[8] = {a.x,a.y,a.z,a.w,b.x,b.y,b.z,b.w};
#pragma unroll
    for (int e = 0; e < 8; e++) { bf16t hh = (bf16t)v[e]; h[e] = hh; l[e] = (bf16t)(v[e] - (float)hh); }
}

// A-operand frags (hi) of row-major [128][128] f32 matrix: m = lane&15, k = q*32+g*8+e
__device__ __forceinline__ void load_fragsH(const float* __restrict__ M, int g, int c, bf16x8 f[8][4]) {
#pragma unroll
    for (int mt = 0; mt < 8; mt++)
#pragma unroll
        for (int q = 0; q < 4; q++)
            f[mt][q] = ld8(M + (mt*16 + c)*DD + q*32 + g*8);
}
__device__ __forceinline__ void load_fragsHL(const float* __restrict__ M, int g, int c,
                                             bf16x8 fh[8][4], bf16x8 fl[8][4]) {
#pragma unroll
    for (int mt = 0; mt < 8; mt++)
#pragma unroll
        for (int q = 0; q < 4; q++)
            ld8hl(M + (mt*16 + c)*DD + q*32 + g*8, fh[mt][q], fl[mt][q]);
}

// X buffer: [128 x 16] state as packed u32 (2 rows per u32). u32 index:
// rowpair rp = row/2; idx = ((rp/4)*16 + col)*4 + rp%4.  1024 u32 = 4KB/plane.
__device__ __forceinline__ void x_write(u32* __restrict__ XHp, u32* __restrict__ XLp,
                                        const f32x4* acc, int g, int c) {
#pragma unroll
    for (int mt = 0; mt < 8; mt++) {
        f32x4 a = acc[mt];
        u32 h0 = pkbf(a[0], a[1]), h1 = pkbf(a[2], a[3]);
        float l0 = a[0] - lo_f(h0), l1 = a[1] - hi_f(h0);
        float l2 = a[2] - lo_f(h1), l3 = a[3] - hi_f(h1);
        u32 q0 = pkbf(l0, l1), q1 = pkbf(l2, l3);
        int base = ((2*mt + (g >> 1))*16 + c)*4 + 2*(g & 1);
        *(u32x2*)(XHp + base) = u32x2{h0, h1};
        *(u32x2*)(XLp + base) = u32x2{q0, q1};
    }
}
// read B-operand frags of X^T: k = q*32+8g+e, n = c(batch)
__device__ __forceinline__ void x_read(const u32* __restrict__ Xp, int g, int c, bf16x8* f) {
#pragma unroll
    for (int q = 0; q < 4; q++) {
        u32x4 v = *(const u32x4*)(Xp + ((4*q + g)*16 + c)*4);
        f[q] = __builtin_bit_cast(bf16x8, v);
    }
}

// stage u_t (coalesced): lane covers batch cb = lane/4, din quarter dq = lane%4
// U plane layout: [q][slot=g*16+cb][4] u32 (1024 u32 = 4KB)
__device__ __forceinline__ void stage_u(const float* __restrict__ u, long c, int t,
                                        int lane, u32* __restrict__ U) {
    int cb = lane >> 2, dq = lane & 3;
    const float* p = u + (long)cb*SEQ*DD + ((long)c*CL + t)*DD + dq*32;
    float v[32];
#pragma unroll
    for (int i = 0; i < 8; i++) *(float4*)(v + 4*i) = *(const float4*)(p + 4*i);
    u32 pk[16];
#pragma unroll
    for (int k = 0; k < 16; k++) pk[k] = pkbf(v[2*k], v[2*k+1]);
#pragma unroll
    for (int g = 0; g < 4; g++)
        *(u32x4*)(U + (dq*256 + g*64 + cb*4)) = u32x4{pk[4*g], pk[4*g+1], pk[4*g+2], pk[4*g+3]};
}
__device__ __forceinline__ void u_read(const u32* __restrict__ U, int lane, bf16x8* f) {
#pragma unroll
    for (int q = 0; q < 4; q++)
        f[q] = __builtin_bit_cast(bf16x8, *(const u32x4*)(U + q*256 + lane*4));
}

// seed X buffer with identity columns 16w..16w+15
__device__ __forceinline__ void seed_ident(u32* __restrict__ XHp, u32* __restrict__ XLp,
                                           int w, int lane) {
    for (int i = lane; i < 1024; i += 64) { XHp[i] = 0u; XLp[i] = 0u; }
    int g = (lane >> 4) & 3, c = lane & 15;
    if (g == 0) {
        int row = 16*w + c;
        int rp = row >> 1;
        XHp[((rp >> 2)*16 + c)*4 + (rp & 3)] = (row & 1) ? 0x3f800000u : 0x00003f80u;
    }
}

// ---------------- pass1: chunk end-states E + P = A^CL ----------------
__global__ __launch_bounds__(128, 1) void k_pass1(const float* __restrict__ u,
                                                  const float* __restrict__ Am,
                                                  const float* __restrict__ Bm,
                                                  float* __restrict__ E,
                                                  float* __restrict__ Pm) {
    __shared__ u32 XH[2][1024], XL[2][1024], UB[3][1024];
    int tid = threadIdx.x, lane = tid & 63, wid = tid >> 6;
    int g = (lane >> 4) & 3, c = lane & 15;
    int bid = blockIdx.x;
    if (bid < NC) {
        long ch = bid;
        if (wid == 0) {
            bf16x8 fA[8][4], fB[8][4];
            load_fragsH(Am, g, c, fA);
            load_fragsH(Bm, g, c, fB);
            f32x4 acc[8];
            __syncthreads();                              // UB[0] staged
            for (int t = 0; t < CL; t++) {
                bf16x8 uf[4];
                u_read(UB[t % 3], lane, uf);
                bf16x8 xh[4], xl[4];
                if (t > 0) { x_read(XH[t & 1], g, c, xh); x_read(XL[t & 1], g, c, xl); }
#pragma unroll
                for (int mt = 0; mt < 8; mt++) {
                    f32x4 a = {0.f, 0.f, 0.f, 0.f};
#pragma unroll
                    for (int q = 0; q < 4; q++) a = MFMA(fB[mt][q], uf[q], a);
                    if (t > 0) {
#pragma unroll
                        for (int q = 0; q < 4; q++) {
                            a = MFMA(fA[mt][q], xh[q], a);
                            a = MFMA(fA[mt][q], xl[q], a);
                        }
                    }
                    acc[mt] = a;
                }
                if (t < CL - 1) x_write(XH[(t+1) & 1], XL[(t+1) & 1], acc, g, c);
                __syncthreads();
            }
#pragma unroll
            for (int mt = 0; mt < 8; mt++)
                *(f32x4*)(E + (ch*8 + mt)*256 + lane*4) = acc[mt];
        } else {
            stage_u(u, ch, 0, lane, UB[0]);
            __syncthreads();
            for (int t = 0; t < CL; t++) {
                if (t + 1 < CL) stage_u(u, ch, t + 1, lane, UB[(t+1) % 3]);
                __syncthreads();
            }
        }
    } else {
        // ident waves: P = A^CL, column block w
        int w = (bid - NC)*2 + wid;
        bf16x8 fA[8][4];
        load_fragsH(Am, g, c, fA);
        u32* xhp = XH[wid]; u32* xlp = XL[wid];
        seed_ident(xhp, xlp, w, lane);
        f32x4 acc[8];
        for (int t = 0; t < CL; t++) {
            bf16x8 xh[4], xl[4];
            x_read(xhp, g, c, xh); x_read(xlp, g, c, xl);
#pragma unroll
            for (int mt = 0; mt < 8; mt++) {
                f32x4 a = {0.f, 0.f, 0.f, 0.f};
#pragma unroll
                for (int q = 0; q < 4; q++) {
                    a = MFMA(fA[mt][q], xh[q], a);
                    a = MFMA(fA[mt][q], xl[q], a);
                }
                acc[mt] = a;
            }
            x_write(xhp, xlp, acc, g, c);
        }
#pragma unroll
        for (int mt = 0; mt < 8; mt++)
#pragma unroll
            for (int r = 0; r < 4; r++)
                Pm[(mt*16 + 4*g + r)*DD + 16*w + c] = acc[mt][r];
    }
}

// ---------------- k_group: E2[g] over GRP chunks + Pg = P^GRP ----------------
__global__ __launch_bounds__(64, 1) void k_group(const float* __restrict__ E,
                                                 const float* __restrict__ Pm,
                                                 float* __restrict__ E2,
                                                 float* __restrict__ Pg) {
    __shared__ u32 XH[2][1024], XL[2][1024];
    int lane = threadIdx.x & 63;
    int g = (lane >> 4) & 3, c = lane & 15;
    int bid = blockIdx.x;
    bf16x8 fPh[8][4], fPl[8][4];
    load_fragsHL(Pm, g, c, fPh, fPl);
    if (bid < NG) {
        f32x4 T[8];
        for (int r = 0; r < GRP; r++) {
            long cc = (long)bid*GRP + r;
            f32x4 e[8];
#pragma unroll
            for (int mt = 0; mt < 8; mt++) e[mt] = *(const f32x4*)(E + (cc*8 + mt)*256 + lane*4);
            if (r > 0) {
                bf16x8 xh[4], xl[4];
                x_read(XH[r & 1], g, c, xh); x_read(XL[r & 1], g, c, xl);
#pragma unroll
                for (int mt = 0; mt < 8; mt++) {
                    f32x4 a = e[mt];
#pragma unroll
                    for (int q = 0; q < 4; q++) {
                        a = MFMA(fPh[mt][q], xh[q], a);
                        a = MFMA(fPh[mt][q], xl[q], a);
                        a = MFMA(fPl[mt][q], xh[q], a);
                    }
                    T[mt] = a;
                }
            } else {
#pragma unroll
                for (int mt = 0; mt < 8; mt++) T[mt] = e[mt];
            }
            if (r < GRP - 1) x_write(XH[(r+1) & 1], XL[(r+1) & 1], T, g, c);
        }
#pragma unroll
        for (int mt = 0; mt < 8; mt++)
            *(f32x4*)(E2 + ((long)bid*8 + mt)*256 + lane*4) = T[mt];
    } else {
        int w = bid - NG;
        seed_ident(XH[0], XL[0], w, lane);
        f32x4 T[8];
        for (int r = 0; r < GRP; r++) {
            bf16x8 xh[4], xl[4];
            x_read(XH[r & 1], g, c, xh); x_read(XL[r & 1], g, c, xl);
#pragma unroll
            for (int mt = 0; mt < 8; mt++) {
                f32x4 a = {0.f, 0.f, 0.f, 0.f};
#pragma unroll
                for (int q = 0; q < 4; q++) {
                    a = MFMA(fPh[mt][q], xh[q], a);
                    a = MFMA(fPh[mt][q], xl[q], a);
                    a = MFMA(fPl[mt][q], xh[q], a);
                }
                T[mt] = a;
            }
            x_write(XH[(r+1) & 1], XL[(r+1) & 1], T, g, c);
        }
#pragma unroll
        for (int mt = 0; mt < 8; mt++)
#pragma unroll
            for (int r = 0; r < 4; r++)
                Pg[(mt*16 + 4*g + r)*DD + 16*w + c] = T[mt][r];
    }
}

// ---------------- k_top: group entry states S2[g] ----------------
__global__ __launch_bounds__(64, 1) void k_top(const float* __restrict__ E2,
                                               const float* __restrict__ Pgm,
                                               float* __restrict__ S2) {
    __shared__ u32 XH[2][1024], XL[2][1024];
    int lane = threadIdx.x & 63;
    int g = (lane >> 4) & 3, c = lane & 15;
    bf16x8 fPh[8][4], fPl[8][4];
    load_fragsHL(Pgm, g, c, fPh, fPl);
    f32x4 T[8];
#pragma unroll
    for (int mt = 0; mt < 8; mt++) T[mt] = f32x4{0.f, 0.f, 0.f, 0.f};
    for (int gg = 0; gg < NG; gg++) {
#pragma unroll
        for (int mt = 0; mt < 8; mt++)
            *(f32x4*)(S2 + ((long)gg*8 + mt)*256 + lane*4) = T[mt];
        if (gg == NG - 1) break;
        f32x4 e[8];
#pragma unroll
        for (int mt = 0; mt < 8; mt++) e[mt] = *(const f32x4*)(E2 + ((long)gg*8 + mt)*256 + lane*4);
        if (gg > 0) {
            bf16x8 xh[4], xl[4];
            x_read(XH[gg & 1], g, c, xh); x_read(XL[gg & 1], g, c, xl);
#pragma unroll
            for (int mt = 0; mt < 8; mt++) {
                f32x4 a = e[mt];
#pragma unroll
                for (int q = 0; q < 4; q++) {
                    a = MFMA(fPh[mt][q], xh[q], a);
                    a = MFMA(fPh[mt][q], xl[q], a);
                    a = MFMA(fPl[mt][q], xh[q], a);
                }
                T[mt] = a;
            }
        } else {
#pragma unroll
            for (int mt = 0; mt < 8; mt++) T[mt] = e[mt];
        }
        x_write(XH[(gg+1) & 1], XL[(gg+1) & 1], T, g, c);
    }
}

// ---------------- k_fix: chunk entry states S[c] (in place over E) ----------------
__global__ __launch_bounds__(64, 1) void k_fix(float* __restrict__ E,
                                               const float* __restrict__ Pm,
                                               const float* __restrict__ S2) {
    __shared__ u32 XH[2][1024], XL[2][1024];
    int lane = threadIdx.x & 63;
    int g = (lane >> 4) & 3, c = lane & 15;
    int gr = blockIdx.x;
    bf16x8 fPh[8][4], fPl[8][4];
    load_fragsHL(Pm, g, c, fPh, fPl);
    f32x4 T[8];
#pragma unroll
    for (int mt = 0; mt < 8; mt++) T[mt] = *(const f32x4*)(S2 + ((long)gr*8 + mt)*256 + lane*4);
    x_write(XH[0], XL[0], T, g, c);
    for (int r = 0; r < GRP; r++) {
        long cc = (long)gr*GRP + r;
        f32x4 e[8];
#pragma unroll
        for (int mt = 0; mt < 8; mt++) e[mt] = *(const f32x4*)(E + (cc*8 + mt)*256 + lane*4);
#pragma unroll
        for (int mt = 0; mt < 8; mt++)
            *(f32x4*)(E + (cc*8 + mt)*256 + lane*4) = T[mt];      // S[c]
        if (r == GRP - 1) break;
        bf16x8 xh[4], xl[4];
        x_read(XH[r & 1], g, c, xh); x_read(XL[r & 1], g, c, xl);
#pragma unroll
        for (int mt = 0; mt < 8; mt++) {
            f32x4 a = e[mt];
#pragma unroll
            for (int q = 0; q < 4; q++) {
                a = MFMA(fPh[mt][q], xh[q], a);
                a = MFMA(fPh[mt][q], xl[q], a);
                a = MFMA(fPl[mt][q], xh[q], a);
            }
            T[mt] = a;
        }
        x_write(XH[(r+1) & 1], XL[(r+1) & 1], T, g, c);
    }
}

// ---------------- pass2: final scan + fused y ----------------
__device__ __forceinline__ void y_emit(const bf16x8 (&fC)[8][4], const bf16x8 (&fD)[8][4],
                                       const u32* __restrict__ XHp, const u32* __restrict__ UBp,
                                       int g, int c, int lane, long tg, float* __restrict__ out) {
    bf16x8 xh[4]; x_read(XHp, g, c, xh);
    bf16x8 uf[4]; u_read(UBp, lane, uf);
#pragma unroll
    for (int mt = 0; mt < 8; mt++) {
        f32x4 a = {0.f, 0.f, 0.f, 0.f};
#pragma unroll
        for (int q = 0; q < 4; q++) {
            a = MFMA(fC[mt][q], xh[q], a);
            a = MFMA(fD[mt][q], uf[q], a);
        }
        *(f32x4*)(out + (long)c*SEQ*DD + tg*DD + mt*16 + 4*g) = a;
    }
}

__global__ __launch_bounds__(128, 1) void k_pass2(const float* __restrict__ u,
                                                  const float* __restrict__ Am,
                                                  const float* __restrict__ Bm,
                                                  const float* __restrict__ Cm,
                                                  const float* __restrict__ Dm,
                                                  const float* __restrict__ S,
                                                  float* __restrict__ out) {
    __shared__ u32 XH[2][1024], XL[2][1024], UB[3][1024];
    int tid = threadIdx.x, lane = tid & 63, wid = tid >> 6;
    int g = (lane >> 4) & 3, c = lane & 15;
    long ch = blockIdx.x;
    if (wid == 0) {
        bf16x8 fA[8][4], fB[8][4];
        load_fragsH(Am, g, c, fA);
        load_fragsH(Bm, g, c, fB);
        {
            f32x4 s0[8];
#pragma unroll
            for (int mt = 0; mt < 8; mt++) s0[mt] = *(const f32x4*)(S + (ch*8 + mt)*256 + lane*4);
            x_write(XH[0], XL[0], s0, g, c);
        }
        __syncthreads();
        for (int t = 0; t < CL; t++) {
            bf16x8 uf[4]; u_read(UB[t % 3], lane, uf);
            bf16x8 xh[4], xl[4];
            x_read(XH[t & 1], g, c, xh); x_read(XL[t & 1], g, c, xl);
            f32x4 acc[8];
#pragma unroll
            for (int mt = 0; mt < 8; mt++) {
                f32x4 a = {0.f, 0.f, 0.f, 0.f};
#pragma unroll
                for (int q = 0; q < 4; q++) a = MFMA(fB[mt][q], uf[q], a);
#pragma unroll
                for (int q = 0; q < 4; q++) {
                    a = MFMA(fA[mt][q], xh[q], a);
                    a = MFMA(fA[mt][q], xl[q], a);
                }
                acc[mt] = a;
            }
            x_write(XH[(t+1) & 1], XL[(t+1) & 1], acc, g, c);   // x_t (w1 reads it)
            __syncthreads();
        }
    } else {
        bf16x8 fC[8][4], fD[8][4];
        load_fragsH(Cm, g, c, fC);
        load_fragsH(Dm, g, c, fD);
        stage_u(u, ch, 0, lane, UB[0]);
        __syncthreads();
        for (int t = 0; t < CL; t++) {
            if (t + 1 < CL) stage_u(u, ch, t + 1, lane, UB[(t+1) % 3]);
            if (t > 0)
                y_emit(fC, fD, XH[t & 1], UB[(t-1) % 3], g, c, lane, ch*CL + (t-1), out);
            __syncthreads();
        }
        y_emit(fC, fD, XH[CL & 1], UB[(CL-1) % 3], g, c, lane, ch*CL + (CL-1), out);
    }
}

extern "C" void kernel_launch(void* const* d_in, const int* in_sizes, int n_in,
                              void* d_out, int out_size, void* d_ws, size_t ws_size,
                              hipStream_t stream) {
    (void)in_sizes; (void)n_in; (void)out_size; (void)ws_size;
    const float* u = (const float*)d_in[0];
    const float* A = (const float*)d_in[1];
    const float* B = (const float*)d_in[2];
    const float* C = (const float*)d_in[3];
    const float* D = (const float*)d_in[4];
    float* out = (float*)d_out;
    float* ws  = (float*)d_ws;
    // ws (floats): E 1,048,576 | E2 65,536 | S2 65,536 | P 16,384 | Pg 16,384
    // total 1,212,416 floats = 4.85 MB
    float* E  = ws;
    float* E2 = E  + (long)NC*2048;
    float* S2 = E2 + (long)NG*2048;
    float* Pm = S2 + (long)NG*2048;
    float* Pg = Pm + 16384;
    k_pass1<<<NC + 4, 128, 0, stream>>>(u, A, B, E, Pm);
    k_group<<<NG + 8, 64, 0, stream>>>(E, Pm, E2, Pg);
    k_top  <<<1,      64, 0, stream>>>(E2, Pg, S2);
    k_fix  <<<NG,     64, 0, stream>>>(E, Pm, S2);
    k_pass2<<<NC,     128, 0, stream>>>(u, A, B, C, D, E, out);
}